// Round 1
// baseline (670.079 us; speedup 1.0000x reference)
//
#include <hip/hip_runtime.h>

#define DEV_INLINE __device__ __forceinline__

typedef __attribute__((ext_vector_type(8))) short bf16x8;
typedef __attribute__((ext_vector_type(4))) float f32x4;

// ---------- bf16 bit helpers (no header dependency) ----------
DEV_INLINE unsigned short f2bf(float f) {
  union { float f; unsigned u; } v; v.f = f;
  unsigned r = v.u + 0x7FFFu + ((v.u >> 16) & 1u);  // round-to-nearest-even
  return (unsigned short)(r >> 16);
}
DEV_INLINE float bf2f(unsigned short u) {
  union { unsigned u; float f; } v; v.u = ((unsigned)u) << 16;
  return v.f;
}
DEV_INLINE float sigmoidf_(float x) { return 1.0f / (1.0f + __expf(-x)); }

DEV_INLINE void gload_lds16(const void* g, void* l) {
  __builtin_amdgcn_global_load_lds(
      (const __attribute__((address_space(1))) void*)(g),
      (__attribute__((address_space(3))) void*)(l), 16, 0, 0);
}

// ---------- fp32 -> bf16 elementwise (x input) ----------
__global__ __launch_bounds__(256)
void f32_to_bf16_kernel(const float* __restrict__ in, unsigned short* __restrict__ out, int n4) {
  int i = blockIdx.x * blockDim.x + threadIdx.x;
  if (i >= n4) return;
  const float4 v = reinterpret_cast<const float4*>(in)[i];
  ushort4 o;
  o.x = f2bf(v.x); o.y = f2bf(v.y); o.z = f2bf(v.z); o.w = f2bf(v.w);
  reinterpret_cast<ushort4*>(out)[i] = o;
}

// ---------- W [K][N] fp32 -> Wt [N][K] bf16 ----------
__global__ __launch_bounds__(256)
void transpose_bf16_kernel(const float* __restrict__ W, unsigned short* __restrict__ Wt,
                           int K, int N) {
  __shared__ float tile[32][33];
  const int tx = threadIdx.x, ty = threadIdx.y;  // blockDim (32,8)
  const int kb = blockIdx.x * 32, nb = blockIdx.y * 32;
  #pragma unroll
  for (int i = 0; i < 32; i += 8)
    tile[ty + i][tx] = W[(size_t)(kb + ty + i) * N + (nb + tx)];
  __syncthreads();
  #pragma unroll
  for (int i = 0; i < 32; i += 8)
    Wt[(size_t)(nb + ty + i) * K + (kb + tx)] = f2bf(tile[tx][ty + i]);
}

// ---------- GEMM + fused gate epilogue ----------
// U[m][n] = gate_n( sum_k A[m][k]*Bt[n][k] )  stored bf16.
// regions (H=512): n>>9==1 -> sigmoid(v+bias[n&511]); ==2 -> sigmoid(v+bias[512+(n&511)]); else v.
__global__ __launch_bounds__(256, 2)
void gemm_gate_kernel(const unsigned short* __restrict__ A,   // [M][K] bf16 bits
                      const unsigned short* __restrict__ Bt,  // [N][K] bf16 bits
                      const float* __restrict__ bias,         // [1024]
                      unsigned short* __restrict__ U,         // [M][N] bf16 bits
                      int N, int K) {
  __shared__ short As[128 * 64];
  __shared__ short Bs[128 * 64];
  const int tid = threadIdx.x;
  const int lane = tid & 63;
  const int l15 = lane & 15;
  const int l4 = lane >> 4;
  const int w = tid >> 6;
  const int wr = (w >> 1) * 64;
  const int wc = (w & 1) * 64;
  const int m0 = blockIdx.x * 128;
  const int n0 = blockIdx.y * 128;

  f32x4 acc[4][4];
  #pragma unroll
  for (int i = 0; i < 4; ++i)
    #pragma unroll
    for (int j = 0; j < 4; ++j)
      acc[i][j] = (f32x4){0.f, 0.f, 0.f, 0.f};

  const unsigned short* Abase = A + (size_t)m0 * K;
  const unsigned short* Bbase = Bt + (size_t)n0 * K;
  const int nsteps = K >> 6;

  for (int t = 0; t < nsteps; ++t) {
    const int k0 = t * 64;
    // stage A tile [128][64] and B tile [128][64]; linear LDS dest,
    // source k-slot pre-swizzled:  phys_slot sl holds global slot sl^(row&7)
    #pragma unroll
    for (int it = 0; it < 4; ++it) {
      int c = it * 256 + tid;
      int row = c >> 3, sl = c & 7;
      int ks = sl ^ (row & 7);
      gload_lds16(Abase + (size_t)row * K + (k0 + ks * 8), &As[c * 8]);
    }
    #pragma unroll
    for (int it = 0; it < 4; ++it) {
      int c = it * 256 + tid;
      int row = c >> 3, sl = c & 7;
      int ks = sl ^ (row & 7);
      gload_lds16(Bbase + (size_t)row * K + (k0 + ks * 8), &Bs[c * 8]);
    }
    __syncthreads();

    const bf16x8* As8 = (const bf16x8*)As;
    const bf16x8* Bs8 = (const bf16x8*)Bs;
    #pragma unroll
    for (int kk = 0; kk < 2; ++kk) {
      bf16x8 af[4], bfr[4];
      #pragma unroll
      for (int i = 0; i < 4; ++i) {
        int r = wr + i * 16 + l15;
        int phys = (kk * 4 + l4) ^ (r & 7);
        af[i] = As8[r * 8 + phys];
      }
      #pragma unroll
      for (int j = 0; j < 4; ++j) {
        int r = wc + j * 16 + l15;
        int phys = (kk * 4 + l4) ^ (r & 7);
        bfr[j] = Bs8[r * 8 + phys];
      }
      #pragma unroll
      for (int i = 0; i < 4; ++i)
        #pragma unroll
        for (int j = 0; j < 4; ++j)
          acc[i][j] = __builtin_amdgcn_mfma_f32_16x16x32_bf16(af[i], bfr[j], acc[i][j], 0, 0, 0);
    }
    __syncthreads();
  }

  // epilogue: gate + store bf16
  #pragma unroll
  for (int i = 0; i < 4; ++i) {
    #pragma unroll
    for (int j = 0; j < 4; ++j) {
      #pragma unroll
      for (int reg = 0; reg < 4; ++reg) {
        int row = m0 + wr + i * 16 + (l4 * 4 + reg);
        int col = n0 + wc + j * 16 + l15;
        float v = acc[i][j][reg];
        int region = col >> 9;
        if (region == 1)      v = sigmoidf_(v + bias[col & 511]);
        else if (region == 2) v = sigmoidf_(v + bias[512 + (col & 511)]);
        U[(size_t)row * N + col] = f2bf(v);
      }
    }
  }
}

// ---------- chunked linear-recurrence scan + highway output ----------
// block: 512 thr = (64 h) x (8 chunks of 128 steps); grid: B * (H/64) = 256
__global__ __launch_bounds__(512)
void scan_kernel(const unsigned short* __restrict__ U, int N, int first,
                 const unsigned short* __restrict__ hin,   // [M][512] bf16 (xres) if !first
                 unsigned short* __restrict__ hout_bf,     // [M][512] bf16 or null
                 float* __restrict__ hout_f32,             // [M][512] f32 or null
                 float* __restrict__ hidden) {             // [B][512]
  const int b = blockIdx.x >> 3;
  const int hl = threadIdx.x & 63;
  const int h = ((blockIdx.x & 7) << 6) + hl;
  const int ch = threadIdx.x >> 6;
  __shared__ float sP[8][64];
  __shared__ float sQ[8][64];
  const size_t row0 = (size_t)b * 1024 + (size_t)ch * 128;

  // pass 1: chunk-local (P, Q) with c_in = 0
  const unsigned short* Up = U + row0 * N;
  float c = 0.f, P = 1.f;
  #pragma unroll 4
  for (int l = 0; l < 128; ++l) {
    float f  = bf2f(Up[512 + h]);
    float xt = bf2f(Up[h]);
    c = f * c + (1.f - f) * xt;
    P *= f;
    Up += N;
  }
  sP[ch][hl] = P;
  sQ[ch][hl] = c;
  __syncthreads();
  float cin = 0.f;
  for (int j = 0; j < ch; ++j) cin = sP[j][hl] * cin + sQ[j][hl];

  // pass 2: real scan + highway write
  c = cin;
  Up = U + row0 * N;
  const unsigned short* hp = first ? (const unsigned short*)nullptr : (hin + row0 * 512 + h);
  size_t oidx = row0 * 512 + h;
  #pragma unroll 4
  for (int l = 0; l < 128; ++l) {
    float f  = bf2f(Up[512 + h]);
    float xt = bf2f(Up[h]);
    c = f * c + (1.f - f) * xt;
    float r  = bf2f(Up[1024 + h]);
    float xr = first ? bf2f(Up[1536 + h]) : bf2f(*hp);
    float o = r * c + (1.f - r) * xr;
    if (hout_bf)  hout_bf[oidx] = f2bf(o);
    if (hout_f32) hout_f32[oidx] = o;
    Up += N;
    if (!first) hp += 512;
    oidx += 512;
  }
  if (ch == 7) hidden[(size_t)b * 512 + h] = c;
}

// ---------- head: projected = h_last @ Wp + bp; out = projected @ Wc + bc ----------
__global__ __launch_bounds__(256)
void proj_kernel(const float* __restrict__ hfull, const float* __restrict__ Wp,
                 const float* __restrict__ bp, const float* __restrict__ Wc,
                 const float* __restrict__ bc, float* __restrict__ out) {
  __shared__ float hl[512];
  __shared__ float pr[512];
  const int b = blockIdx.x, t = threadIdx.x;
  const float* hrow = hfull + ((size_t)b * 1024 + 1023) * 512;
  hl[t] = hrow[t];
  hl[t + 256] = hrow[t + 256];
  __syncthreads();
  for (int j = t; j < 512; j += 256) {
    float s = 0.f;
    for (int k = 0; k < 512; ++k) s += hl[k] * Wp[(size_t)k * 512 + j];
    pr[j] = s + bp[j];
  }
  __syncthreads();
  if (t < 16) {
    float s = 0.f;
    for (int k = 0; k < 512; ++k) s += pr[k] * Wc[k * 16 + t];
    out[b * 16 + t] = s + bc[t];
  }
}

extern "C" void kernel_launch(void* const* d_in, const int* in_sizes, int n_in,
                              void* d_out, int out_size, void* d_ws, size_t ws_size,
                              hipStream_t stream) {
  const float* x  = (const float*)d_in[0];
  const float* W0 = (const float*)d_in[1];
  const float* b0 = (const float*)d_in[2];
  const float* W1 = (const float*)d_in[3];
  const float* b1 = (const float*)d_in[4];
  const float* W2 = (const float*)d_in[5];
  const float* b2 = (const float*)d_in[6];
  const float* W3 = (const float*)d_in[7];
  const float* b3 = (const float*)d_in[8];
  const float* Wp = (const float*)d_in[9];
  const float* bp = (const float*)d_in[10];
  const float* Wc = (const float*)d_in[11];
  const float* bc = (const float*)d_in[12];

  float* out = (float*)d_out;
  float* outO = out;                                   // (32,16)
  float* outH = out + 512;                             // (32,1024,512)
  float* outHid = out + 512 + (size_t)32 * 1024 * 512; // (4,32,512)

  char* ws = (char*)d_ws;
  size_t off = 0;
  auto alloc = [&](size_t bytes) {
    void* p = ws + off;
    off += (bytes + 255) & ~(size_t)255;
    return p;
  };
  unsigned short* Wt0 = (unsigned short*)alloc((size_t)2048 * 256 * 2);
  unsigned short* Wt1 = (unsigned short*)alloc((size_t)1536 * 512 * 2);
  unsigned short* Wt2 = (unsigned short*)alloc((size_t)1536 * 512 * 2);
  unsigned short* Wt3 = (unsigned short*)alloc((size_t)1536 * 512 * 2);
  unsigned short* xbf = (unsigned short*)alloc((size_t)32768 * 256 * 2);
  unsigned short* h0  = (unsigned short*)alloc((size_t)32768 * 512 * 2);
  unsigned short* h1  = (unsigned short*)alloc((size_t)32768 * 512 * 2);
  unsigned short* Ubf = (unsigned short*)alloc((size_t)32768 * 2048 * 2);
  (void)ws_size; (void)in_sizes; (void)n_in; (void)out_size;

  f32_to_bf16_kernel<<<8192, 256, 0, stream>>>(x, xbf, 8388608 / 4);
  transpose_bf16_kernel<<<dim3(8, 64),  dim3(32, 8), 0, stream>>>(W0, Wt0, 256, 2048);
  transpose_bf16_kernel<<<dim3(16, 48), dim3(32, 8), 0, stream>>>(W1, Wt1, 512, 1536);
  transpose_bf16_kernel<<<dim3(16, 48), dim3(32, 8), 0, stream>>>(W2, Wt2, 512, 1536);
  transpose_bf16_kernel<<<dim3(16, 48), dim3(32, 8), 0, stream>>>(W3, Wt3, 512, 1536);

  // layer 0: K=256, N=2048 (xt | f | r | xres)
  gemm_gate_kernel<<<dim3(256, 16), 256, 0, stream>>>(xbf, Wt0, b0, Ubf, 2048, 256);
  scan_kernel<<<256, 512, 0, stream>>>(Ubf, 2048, 1, nullptr, h0, nullptr, outHid + 0);
  // layer 1
  gemm_gate_kernel<<<dim3(256, 12), 256, 0, stream>>>(h0, Wt1, b1, Ubf, 1536, 512);
  scan_kernel<<<256, 512, 0, stream>>>(Ubf, 1536, 0, h0, h1, nullptr, outHid + 16384);
  // layer 2
  gemm_gate_kernel<<<dim3(256, 12), 256, 0, stream>>>(h1, Wt2, b2, Ubf, 1536, 512);
  scan_kernel<<<256, 512, 0, stream>>>(Ubf, 1536, 0, h1, h0, nullptr, outHid + 32768);
  // layer 3: write final h as fp32 straight to d_out
  gemm_gate_kernel<<<dim3(256, 12), 256, 0, stream>>>(h0, Wt3, b3, Ubf, 1536, 512);
  scan_kernel<<<256, 512, 0, stream>>>(Ubf, 1536, 0, h0, nullptr, outH, outHid + 49152);

  proj_kernel<<<32, 256, 0, stream>>>(outH, Wp, bp, Wc, bc, outO);
}

// Round 2
// 567.635 us; speedup vs baseline: 1.1805x; 1.1805x over previous
//
#include <hip/hip_runtime.h>

#define DEV_INLINE __device__ __forceinline__

typedef __attribute__((ext_vector_type(8))) short bf16x8;
typedef __attribute__((ext_vector_type(4))) float f32x4;

// ---------- bf16 bit helpers ----------
DEV_INLINE unsigned short f2bf(float f) {
  union { float f; unsigned u; } v; v.f = f;
  unsigned r = v.u + 0x7FFFu + ((v.u >> 16) & 1u);  // round-to-nearest-even
  return (unsigned short)(r >> 16);
}
DEV_INLINE float bf2f(unsigned short u) {
  union { unsigned u; float f; } v; v.u = ((unsigned)u) << 16;
  return v.f;
}
DEV_INLINE float sigmoidf_(float x) { return 1.0f / (1.0f + __expf(-x)); }

DEV_INLINE void gload_lds16(const void* g, void* l) {
  __builtin_amdgcn_global_load_lds(
      (const __attribute__((address_space(1))) void*)(g),
      (__attribute__((address_space(3))) void*)(l), 16, 0, 0);
}

// ---------- fp32 -> bf16 elementwise (x input) ----------
__global__ __launch_bounds__(256)
void f32_to_bf16_kernel(const float* __restrict__ in, unsigned short* __restrict__ out, int n4) {
  int i = blockIdx.x * blockDim.x + threadIdx.x;
  if (i >= n4) return;
  const float4 v = reinterpret_cast<const float4*>(in)[i];
  ushort4 o;
  o.x = f2bf(v.x); o.y = f2bf(v.y); o.z = f2bf(v.z); o.w = f2bf(v.w);
  reinterpret_cast<ushort4*>(out)[i] = o;
}

// ---------- W [K][N] fp32 -> Wt [N][K] bf16 ----------
__global__ __launch_bounds__(256)
void transpose_bf16_kernel(const float* __restrict__ W, unsigned short* __restrict__ Wt,
                           int K, int N) {
  __shared__ float tile[32][33];
  const int tx = threadIdx.x, ty = threadIdx.y;  // blockDim (32,8)
  const int kb = blockIdx.x * 32, nb = blockIdx.y * 32;
  #pragma unroll
  for (int i = 0; i < 32; i += 8)
    tile[ty + i][tx] = W[(size_t)(kb + ty + i) * N + (nb + tx)];
  __syncthreads();
  #pragma unroll
  for (int i = 0; i < 32; i += 8)
    Wt[(size_t)(nb + ty + i) * K + (kb + tx)] = f2bf(tile[tx][ty + i]);
}

// ---------- GEMM + fused gate epilogue (m97 128x128 structure) ----------
// U[m][n] = gate_n( sum_k A[m][k]*Bt[n][k] )  stored bf16.
// regions (H=512): n>>9==1 -> sigmoid(v+bias[n&511]); ==2 -> sigmoid(v+bias[512+(n&511)]); else v.
__global__ __launch_bounds__(256, 2)
void gemm_gate_kernel(const unsigned short* __restrict__ A,   // [M][K] bf16 bits
                      const unsigned short* __restrict__ Bt,  // [N][K] bf16 bits
                      const float* __restrict__ bias,         // [1024]
                      unsigned short* __restrict__ U,         // [M][N] bf16 bits
                      int N, int K, int NTN) {
  __shared__ short smem[2 * 128 * 64];
  short* As = smem;
  short* Bs = smem + 128 * 64;

  const int tid = threadIdx.x;
  const int lane = tid & 63;
  const int l15 = lane & 15;
  const int l4 = lane >> 4;
  const int w = tid >> 6;
  const int wr = (w >> 1) * 64;
  const int wc = (w & 1) * 64;

  // XCD-aware bijective swizzle, then ntile-fast decomposition for L2 reuse.
  const int nwg = gridDim.x;            // multiple of 8 (4096 or 3072)
  const int cpx = nwg >> 3;
  const int swz = (blockIdx.x & 7) * cpx + (blockIdx.x >> 3);
  const int mtile = swz / NTN;
  const int ntile = swz - mtile * NTN;
  const int m0 = mtile * 128;
  const int n0 = ntile * 128;

  f32x4 acc[4][4];
  #pragma unroll
  for (int i = 0; i < 4; ++i)
    #pragma unroll
    for (int j = 0; j < 4; ++j)
      acc[i][j] = (f32x4){0.f, 0.f, 0.f, 0.f};

  const unsigned short* Abase = A + (size_t)m0 * K;
  const unsigned short* Bbase = Bt + (size_t)n0 * K;
  const int nsteps = K >> 6;

  for (int t = 0; t < nsteps; ++t) {
    const int k0 = t * 64;
    // stage A tile [128][64] and B tile [128][64]; linear LDS dest,
    // source k-slot pre-swizzled: phys_slot sl holds global slot sl^(row&7)
    #pragma unroll
    for (int it = 0; it < 4; ++it) {
      int c = it * 256 + tid;
      int row = c >> 3, sl = c & 7;
      int ks = sl ^ (row & 7);
      gload_lds16(Abase + (size_t)row * K + (k0 + ks * 8), &As[c * 8]);
    }
    #pragma unroll
    for (int it = 0; it < 4; ++it) {
      int c = it * 256 + tid;
      int row = c >> 3, sl = c & 7;
      int ks = sl ^ (row & 7);
      gload_lds16(Bbase + (size_t)row * K + (k0 + ks * 8), &Bs[c * 8]);
    }
    __syncthreads();

    const bf16x8* As8 = (const bf16x8*)As;
    const bf16x8* Bs8 = (const bf16x8*)Bs;
    #pragma unroll
    for (int kk = 0; kk < 2; ++kk) {
      bf16x8 af[4], bfr[4];
      #pragma unroll
      for (int i = 0; i < 4; ++i) {
        int r = wr + i * 16 + l15;
        int phys = (kk * 4 + l4) ^ (r & 7);
        af[i] = As8[r * 8 + phys];
      }
      #pragma unroll
      for (int j = 0; j < 4; ++j) {
        int r = wc + j * 16 + l15;
        int phys = (kk * 4 + l4) ^ (r & 7);
        bfr[j] = Bs8[r * 8 + phys];
      }
      #pragma unroll
      for (int i = 0; i < 4; ++i)
        #pragma unroll
        for (int j = 0; j < 4; ++j)
          acc[i][j] = __builtin_amdgcn_mfma_f32_16x16x32_bf16(af[i], bfr[j], acc[i][j], 0, 0, 0);
    }
    __syncthreads();
  }

  // ---- epilogue: gate, repack via LDS, vectorized 16B stores ----
  // Reuse smem as a 64 x 144 bf16 tile (XOR-swizzled cols), two passes of 64 rows.
  short* eps = smem;
  const int EL = 144;
  #pragma unroll
  for (int p = 0; p < 2; ++p) {
    __syncthreads();
    #pragma unroll
    for (int ii = 0; ii < 2; ++ii) {
      const int i = 2 * p + ii;
      #pragma unroll
      for (int j = 0; j < 4; ++j) {
        const int cg = n0 + wc + j * 16 + l15;
        const int region = cg >> 9;     // wave-uniform per j
        #pragma unroll
        for (int reg = 0; reg < 4; ++reg) {
          float v = acc[i][j][reg];
          if (region == 1)      v = sigmoidf_(v + bias[cg & 511]);
          else if (region == 2) v = sigmoidf_(v + bias[512 + (cg & 511)]);
          const int lr = (wr >> 1) + ii * 16 + l4 * 4 + reg;   // [0,64)
          const int col = (wc + j * 16 + l15) ^ (((lr >> 2) & 3) << 3);
          eps[lr * EL + col] = (short)f2bf(v);
        }
      }
    }
    __syncthreads();
    const int lr2 = tid >> 2;                       // [0,64)
    const int grow = m0 + ((lr2 >> 5) << 6) + (2 * p + ((lr2 >> 4) & 1)) * 16 + (lr2 & 15);
    const int xorv = ((lr2 >> 2) & 3) << 3;
    unsigned short* urow = U + (size_t)grow * N + n0;
    #pragma unroll
    for (int k = 0; k < 4; ++k) {
      const int col = (tid & 3) * 8 + k * 32;
      bf16x8 vv = *(const bf16x8*)&eps[lr2 * EL + (col ^ xorv)];
      *(bf16x8*)(urow + col) = vv;
    }
  }
}

// ---------- chunked linear-recurrence scan, vectorized 8 h / lane ----------
// grid: 32 b x 8 hslices = 256 blocks; block: 512 thr = 64 chunks(16 steps) x 8 hv
__global__ __launch_bounds__(512)
void scan_kernel(const unsigned short* __restrict__ U, int N, int first,
                 const unsigned short* __restrict__ hin,   // [M][512] bf16 (xres) if !first
                 unsigned short* __restrict__ hout_bf,     // [M][512] bf16 or null
                 float* __restrict__ hout_f32,             // [M][512] f32 or null
                 float* __restrict__ hidden) {             // [B][512]
  const int b = blockIdx.x >> 3;
  const int hslice = blockIdx.x & 7;
  const int hv = threadIdx.x & 7;
  const int ch = threadIdx.x >> 3;
  const int h0 = (hslice << 6) + (hv << 3);
  __shared__ float sP[64 * 68];
  __shared__ float sQ[64 * 68];

  const size_t rowBase = (size_t)b * 1024 + (size_t)ch * 16;
  const unsigned short* Uxt = U + rowBase * N + h0;

  // pass 1: chunk-local (P, Q) with c_in = 0
  float c[8], P[8];
  #pragma unroll
  for (int j = 0; j < 8; ++j) { c[j] = 0.f; P[j] = 1.f; }
  {
    const unsigned short* px = Uxt;
    const unsigned short* pf = Uxt + 512;
    #pragma unroll 2
    for (int l = 0; l < 16; ++l) {
      bf16x8 xv = *(const bf16x8*)px;
      bf16x8 fv = *(const bf16x8*)pf;
      #pragma unroll
      for (int j = 0; j < 8; ++j) {
        float f  = bf2f((unsigned short)fv[j]);
        float xt = bf2f((unsigned short)xv[j]);
        c[j] = f * c[j] + (1.f - f) * xt;
        P[j] *= f;
      }
      px += N; pf += N;
    }
  }
  float* myP = &sP[ch * 68 + hv * 8];
  float* myQ = &sQ[ch * 68 + hv * 8];
  #pragma unroll
  for (int j = 0; j < 8; ++j) { myP[j] = P[j]; myQ[j] = c[j]; }
  __syncthreads();

  // Hillis-Steele inclusive affine scan over chunks: T[ch] = t_ch ∘ ... ∘ t_0
  for (int s = 1; s < 64; s <<= 1) {
    float pp[8], pq[8];
    const bool act = (ch >= s);
    if (act) {
      const float* qP = &sP[(ch - s) * 68 + hv * 8];
      const float* qQ = &sQ[(ch - s) * 68 + hv * 8];
      #pragma unroll
      for (int j = 0; j < 8; ++j) { pp[j] = qP[j]; pq[j] = qQ[j]; }
    }
    __syncthreads();
    if (act) {
      #pragma unroll
      for (int j = 0; j < 8; ++j) {
        c[j] = P[j] * pq[j] + c[j];   // self ∘ partner
        P[j] = P[j] * pp[j];
        myP[j] = P[j]; myQ[j] = c[j];
      }
    }
    __syncthreads();
  }

  float cc[8];
  if (ch == 0) {
    #pragma unroll
    for (int j = 0; j < 8; ++j) cc[j] = 0.f;
  } else {
    const float* qQ = &sQ[(ch - 1) * 68 + hv * 8];
    #pragma unroll
    for (int j = 0; j < 8; ++j) cc[j] = qQ[j];
  }

  // pass 2: real scan + highway write
  const unsigned short* px = Uxt;
  const unsigned short* pf = Uxt + 512;
  const unsigned short* pr = Uxt + 1024;
  const unsigned short* pxr = first ? (Uxt + 1536) : (hin + rowBase * 512 + h0);
  const int xr_stride = first ? N : 512;
  unsigned short* ob = hout_bf ? hout_bf + rowBase * 512 + h0 : (unsigned short*)nullptr;
  float* of = hout_f32 ? hout_f32 + rowBase * 512 + h0 : (float*)nullptr;
  #pragma unroll 2
  for (int l = 0; l < 16; ++l) {
    bf16x8 xv = *(const bf16x8*)px;
    bf16x8 fv = *(const bf16x8*)pf;
    bf16x8 rv = *(const bf16x8*)pr;
    bf16x8 xrv = *(const bf16x8*)pxr;
    bf16x8 obuf;
    float o0, o1, o2, o3, o4, o5, o6, o7;
    float ofl[8];
    #pragma unroll
    for (int j = 0; j < 8; ++j) {
      float f  = bf2f((unsigned short)fv[j]);
      float xt = bf2f((unsigned short)xv[j]);
      cc[j] = f * cc[j] + (1.f - f) * xt;
      float r  = bf2f((unsigned short)rv[j]);
      float xr = bf2f((unsigned short)xrv[j]);
      float o = r * cc[j] + (1.f - r) * xr;
      obuf[j] = (short)f2bf(o);
      ofl[j] = o;
    }
    if (ob) { *(bf16x8*)ob = obuf; ob += 512; }
    if (of) {
      float4 v0 = make_float4(ofl[0], ofl[1], ofl[2], ofl[3]);
      float4 v1 = make_float4(ofl[4], ofl[5], ofl[6], ofl[7]);
      *(float4*)of = v0;
      *(float4*)(of + 4) = v1;
      of += 512;
    }
    px += N; pf += N; pr += N; pxr += xr_stride;
  }
  if (ch == 63) {
    #pragma unroll
    for (int j = 0; j < 8; ++j) hidden[(size_t)b * 512 + h0 + j] = cc[j];
  }
}

// ---------- head ----------
__global__ __launch_bounds__(256)
void proj_kernel(const float* __restrict__ hfull, const float* __restrict__ Wp,
                 const float* __restrict__ bp, const float* __restrict__ Wc,
                 const float* __restrict__ bc, float* __restrict__ out) {
  __shared__ float hl[512];
  __shared__ float pr[512];
  const int b = blockIdx.x, t = threadIdx.x;
  const float* hrow = hfull + ((size_t)b * 1024 + 1023) * 512;
  hl[t] = hrow[t];
  hl[t + 256] = hrow[t + 256];
  __syncthreads();
  for (int j = t; j < 512; j += 256) {
    float s = 0.f;
    for (int k = 0; k < 512; ++k) s += hl[k] * Wp[(size_t)k * 512 + j];
    pr[j] = s + bp[j];
  }
  __syncthreads();
  if (t < 16) {
    float s = 0.f;
    for (int k = 0; k < 512; ++k) s += pr[k] * Wc[k * 16 + t];
    out[b * 16 + t] = s + bc[t];
  }
}

extern "C" void kernel_launch(void* const* d_in, const int* in_sizes, int n_in,
                              void* d_out, int out_size, void* d_ws, size_t ws_size,
                              hipStream_t stream) {
  const float* x  = (const float*)d_in[0];
  const float* W0 = (const float*)d_in[1];
  const float* b0 = (const float*)d_in[2];
  const float* W1 = (const float*)d_in[3];
  const float* b1 = (const float*)d_in[4];
  const float* W2 = (const float*)d_in[5];
  const float* b2 = (const float*)d_in[6];
  const float* W3 = (const float*)d_in[7];
  const float* b3 = (const float*)d_in[8];
  const float* Wp = (const float*)d_in[9];
  const float* bp = (const float*)d_in[10];
  const float* Wc = (const float*)d_in[11];
  const float* bc = (const float*)d_in[12];

  float* out = (float*)d_out;
  float* outO = out;                                   // (32,16)
  float* outH = out + 512;                             // (32,1024,512)
  float* outHid = out + 512 + (size_t)32 * 1024 * 512; // (4,32,512)

  char* ws = (char*)d_ws;
  size_t off = 0;
  auto alloc = [&](size_t bytes) {
    void* p = ws + off;
    off += (bytes + 255) & ~(size_t)255;
    return p;
  };
  unsigned short* Wt0 = (unsigned short*)alloc((size_t)2048 * 256 * 2);
  unsigned short* Wt1 = (unsigned short*)alloc((size_t)1536 * 512 * 2);
  unsigned short* Wt2 = (unsigned short*)alloc((size_t)1536 * 512 * 2);
  unsigned short* Wt3 = (unsigned short*)alloc((size_t)1536 * 512 * 2);
  unsigned short* xbf = (unsigned short*)alloc((size_t)32768 * 256 * 2);
  unsigned short* h0  = (unsigned short*)alloc((size_t)32768 * 512 * 2);
  unsigned short* h1  = (unsigned short*)alloc((size_t)32768 * 512 * 2);
  unsigned short* Ubf = (unsigned short*)alloc((size_t)32768 * 2048 * 2);
  (void)ws_size; (void)in_sizes; (void)n_in; (void)out_size;

  f32_to_bf16_kernel<<<8192, 256, 0, stream>>>(x, xbf, 8388608 / 4);
  transpose_bf16_kernel<<<dim3(8, 64),  dim3(32, 8), 0, stream>>>(W0, Wt0, 256, 2048);
  transpose_bf16_kernel<<<dim3(16, 48), dim3(32, 8), 0, stream>>>(W1, Wt1, 512, 1536);
  transpose_bf16_kernel<<<dim3(16, 48), dim3(32, 8), 0, stream>>>(W2, Wt2, 512, 1536);
  transpose_bf16_kernel<<<dim3(16, 48), dim3(32, 8), 0, stream>>>(W3, Wt3, 512, 1536);

  // layer 0: K=256, N=2048 (xt | f | r | xres)
  gemm_gate_kernel<<<256 * 16, 256, 0, stream>>>(xbf, Wt0, b0, Ubf, 2048, 256, 16);
  scan_kernel<<<256, 512, 0, stream>>>(Ubf, 2048, 1, nullptr, h0, nullptr, outHid + 0);
  // layer 1
  gemm_gate_kernel<<<256 * 12, 256, 0, stream>>>(h0, Wt1, b1, Ubf, 1536, 512, 12);
  scan_kernel<<<256, 512, 0, stream>>>(Ubf, 1536, 0, h0, h1, nullptr, outHid + 16384);
  // layer 2
  gemm_gate_kernel<<<256 * 12, 256, 0, stream>>>(h1, Wt2, b2, Ubf, 1536, 512, 12);
  scan_kernel<<<256, 512, 0, stream>>>(Ubf, 1536, 0, h1, h0, nullptr, outHid + 32768);
  // layer 3: write final h as fp32 straight to d_out
  gemm_gate_kernel<<<256 * 12, 256, 0, stream>>>(h0, Wt3, b3, Ubf, 1536, 512, 12);
  scan_kernel<<<256, 512, 0, stream>>>(Ubf, 1536, 0, h0, nullptr, outH, outHid + 49152);

  proj_kernel<<<32, 256, 0, stream>>>(outH, Wp, bp, Wc, bc, outO);
}